// Round 7
// baseline (270.574 us; speedup 1.0000x reference)
//
#include <hip/hip_runtime.h>

#define GN_EPS 1e-5f

// NOTE: node ids packed as (src<<16)|bf16(weight) in csr_ew; requires n < 65536.
// CSR rows are PADDED to multiples of 8 with zero entries (src 0, weight 0.0);
// pad slots are written by k_scanfinal (no giant memset).
// CSR build is ATOMIC-FREE (global): per-chunk LDS histogram with packed u16
// counters gives degree counts AND per-edge within-chunk slots; a prefix pass
// over the per-chunk count table gives global slots.
// GEMMs stage only B (W^T) in LDS (A has no cross-wave reuse).
// GraphNorm finalize is computed REDUNDANTLY PER BLOCK in the consuming kernel
// (64x128 partials are L2-resident; ~64KB reads/block) -- this removes the
// k_finstats dispatches without any grid-wide signaling. In-kernel signaling
// via __threadfence costs an L2 writeback PER BLOCK on multi-XCD CDNA4 (R5:
// 4-30x slowdown). Do NOT re-fuse that way.
// k_fill and layer-1 GEMM are independent -> one grid-concat kernel.

#define HIST_C 64
#define SCAN_CHUNK 4096
#define LDK 136

typedef __attribute__((ext_vector_type(8))) short short8;
typedef __attribute__((ext_vector_type(4))) float f32x4;

__device__ __forceinline__ unsigned short f2bf(float f) {
    unsigned u = __float_as_uint(f);
    u += 0x7fffu + ((u >> 16) & 1u);   // round-to-nearest-even
    return (unsigned short)(u >> 16);
}
__device__ __forceinline__ float bflo(unsigned u) { return __uint_as_float(u << 16); }
__device__ __forceinline__ float bfhi(unsigned u) { return __uint_as_float(u & 0xffff0000u); }

// ---------------- fused weight prep + pS/pQ zero + LDS-histogram count ----------------
__global__ __launch_bounds__(256) void k_prep_hist(const float* __restrict__ W1,
                                                   const float* __restrict__ W2,
                                                   const float* __restrict__ W3,
                                                   const float* __restrict__ Wo,
                                                   const float* __restrict__ b3,
                                                   const float* __restrict__ bo,
                                                   unsigned short* __restrict__ Wt,
                                                   float* __restrict__ M,
                                                   float* __restrict__ mb,
                                                   float* __restrict__ pS,
                                                   float* __restrict__ pQ,
                                                   const int* __restrict__ dst,
                                                   unsigned short* __restrict__ cnt,
                                                   unsigned short* __restrict__ pos,
                                                   int e, int n, int chunk) {
    __shared__ __align__(16) unsigned bins[32768];   // 128 KB: 2 u16 counters / u32
    if (blockIdx.x < 2) {
        unsigned short* sT = (unsigned short*)bins;  // 128*130 u16 alias
        const float* W = blockIdx.x == 0 ? W1 : W2;
        unsigned short* o = Wt + blockIdx.x * 16384;
        const float4* W4 = (const float4*)W;
        for (int idx = threadIdx.x; idx < 128 * 32; idx += 256) {
            int k = idx >> 5, c4 = idx & 31;
            float4 v = W4[k * 32 + c4];
            sT[(c4 * 4 + 0) * 130 + k] = f2bf(v.x);
            sT[(c4 * 4 + 1) * 130 + k] = f2bf(v.y);
            sT[(c4 * 4 + 2) * 130 + k] = f2bf(v.z);
            sT[(c4 * 4 + 3) * 130 + k] = f2bf(v.w);
        }
        __syncthreads();
        for (int idx = threadIdx.x; idx < 128 * 128; idx += 256) {
            int c = idx >> 7, k = idx & 127;
            o[idx] = sT[c * 130 + k];
        }
    } else if (blockIdx.x == 2) {
        // zero the GraphNorm partial slots (2 layers x 64 slots x 128 cols)
        float4 z4 = make_float4(0.f, 0.f, 0.f, 0.f);
        for (int i = threadIdx.x; i < 4096; i += 256) {
            ((float4*)pS)[i] = z4;
            ((float4*)pQ)[i] = z4;
        }
        int k = threadIdx.x;
        if (k < 128) {
            float m0 = 0.f, m1 = 0.f;
            for (int c = 0; c < 128; ++c) {
                float w = W3[k * 128 + c];
                m0 += w * Wo[c * 2];
                m1 += w * Wo[c * 2 + 1];
            }
            M[k * 2] = m0;
            M[k * 2 + 1] = m1;
            if (k < 2) {
                float s = 0.f;
                for (int c = 0; c < 128; ++c) s += b3[c] * Wo[c * 2 + k];
                mb[k] = s + bo[k];
            }
        }
    } else {
        const int c = (int)blockIdx.x - 3;
        const int c0 = c * chunk;
        const int c1 = (c0 + chunk < e) ? c0 + chunk : e;
        const int nw = (n + 1) >> 1;
        for (int i = threadIdx.x; i < nw; i += 256) bins[i] = 0u;
        __syncthreads();
        const bool al = ((size_t)dst & 15) == 0;
        for (int i = c0 + (int)threadIdx.x * 4; i < c1; i += 1024) {
            if (al && i + 3 < c1) {
                int4 d4 = *(const int4*)(dst + i);
                unsigned o0 = atomicAdd(&bins[(unsigned)d4.x >> 1],
                                        (d4.x & 1) ? 0x10000u : 1u);
                unsigned o1 = atomicAdd(&bins[(unsigned)d4.y >> 1],
                                        (d4.y & 1) ? 0x10000u : 1u);
                unsigned o2 = atomicAdd(&bins[(unsigned)d4.z >> 1],
                                        (d4.z & 1) ? 0x10000u : 1u);
                unsigned o3 = atomicAdd(&bins[(unsigned)d4.w >> 1],
                                        (d4.w & 1) ? 0x10000u : 1u);
                ushort4 p;
                p.x = (unsigned short)((o0 >> ((d4.x & 1) * 16)) & 0xffffu);
                p.y = (unsigned short)((o1 >> ((d4.y & 1) * 16)) & 0xffffu);
                p.z = (unsigned short)((o2 >> ((d4.z & 1) * 16)) & 0xffffu);
                p.w = (unsigned short)((o3 >> ((d4.w & 1) * 16)) & 0xffffu);
                *(ushort4*)(pos + i) = p;
            } else {
                for (int k = i; k < c1 && k < i + 4; ++k) {
                    int d = dst[k];
                    unsigned old = atomicAdd(&bins[(unsigned)d >> 1],
                                             (d & 1) ? 0x10000u : 1u);
                    pos[k] = (unsigned short)((old >> ((d & 1) * 16)) & 0xffffu);
                }
            }
        }
        __syncthreads();
        unsigned short* cr = cnt + (size_t)c * n;
        if ((n & 1) == 0) {
            unsigned* cr32 = (unsigned*)cr;
            for (int i = threadIdx.x; i < (n >> 1); i += 256) cr32[i] = bins[i];
        } else {
            for (int i = threadIdx.x; i < n; i += 256)
                cr[i] = (unsigned short)((bins[i >> 1] >> ((i & 1) * 16)) & 0xffffu);
        }
    }
}

// ---------------- cross-chunk prefix + degree + per-256-node padded partials ----------------
__global__ __launch_bounds__(256) void k_reduce(unsigned short* __restrict__ cnt,
                                                int* __restrict__ degi,
                                                int* __restrict__ partial,
                                                int n, int nchunks) {
    int node = blockIdx.x * 256 + threadIdx.x;
    int pdeg = 0;
    if (node < n) {
        int s = 0;
        int cb = 0;
        for (; cb + 8 <= nchunks; cb += 8) {
            int v[8];
            #pragma unroll
            for (int q = 0; q < 8; ++q) v[q] = cnt[(size_t)(cb + q) * n + node];
            #pragma unroll
            for (int q = 0; q < 8; ++q) {
                cnt[(size_t)(cb + q) * n + node] = (unsigned short)s;
                s += v[q];
            }
        }
        for (; cb < nchunks; ++cb) {
            size_t id = (size_t)cb * n + node;
            int v = cnt[id];
            cnt[id] = (unsigned short)s;
            s += v;
        }
        degi[node] = s;
        pdeg = (s + 7) & ~7;
    }
    #pragma unroll
    for (int off = 32; off; off >>= 1) pdeg += __shfl_down(pdeg, off);
    __shared__ int ws[4];
    if ((threadIdx.x & 63) == 0) ws[threadIdx.x >> 6] = pdeg;
    __syncthreads();
    if (threadIdx.x == 0) partial[blockIdx.x] = ws[0] + ws[1] + ws[2] + ws[3];
}

// block b: base = sum(partial[0..b*16-1]); also writes CSR pad slots (zeros)
__global__ __launch_bounds__(256) void k_scanfinal(const int* __restrict__ degi,
                                                   const int* __restrict__ partial,
                                                   int* __restrict__ rowptr,
                                                   float* __restrict__ dinv,
                                                   unsigned* __restrict__ csr_ew,
                                                   int n, int nb) {
    int blockbase = 0;
    for (int i = 0; i < (int)blockIdx.x * 16; ++i) blockbase += partial[i];

    int base = blockIdx.x * SCAN_CHUNK + threadIdx.x * 16;
    int v[16], pv[16];
    int s = 0;
    #pragma unroll
    for (int q = 0; q < 16; ++q) {
        int i = base + q;
        v[q] = (i < n) ? degi[i] : 0;
        pv[q] = (v[q] + 7) & ~7;
        s += pv[q];
    }
    const int lane = threadIdx.x & 63;
    const int wid = threadIdx.x >> 6;
    int x = s;
    #pragma unroll
    for (int off = 1; off < 64; off <<= 1) {
        int t = __shfl_up(x, off);
        if (lane >= off) x += t;
    }
    __shared__ int ws[4];
    if (lane == 63) ws[wid] = x;
    __syncthreads();
    int waveoff = 0;
    if (wid > 0) waveoff += ws[0];
    if (wid > 1) waveoff += ws[1];
    if (wid > 2) waveoff += ws[2];
    int excl = x - s + waveoff + blockbase;
    #pragma unroll
    for (int q = 0; q < 16; ++q) {
        int i = base + q;
        if (i < n) {
            rowptr[i] = excl;
            dinv[i] = rsqrtf((float)(v[q] + 1));
            for (int z = v[q]; z < pv[q]; ++z) csr_ew[excl + z] = 0u;  // pad slots
        }
        excl += pv[q];
    }
    if ((int)blockIdx.x == nb - 1 && threadIdx.x == 255) {
        rowptr[n] = excl;
    }
}

// ---------------- fused CSR fill + layer-1 MFMA GEMM (independent work) ----------------
__global__ __launch_bounds__(256) void k_fillgemm(const float* __restrict__ X,
                                                  const unsigned short* __restrict__ Wt,
                                                  unsigned short* __restrict__ Y,
                                                  const int* __restrict__ src,
                                                  const int* __restrict__ dst,
                                                  const unsigned short* __restrict__ pos,
                                                  const unsigned short* __restrict__ pref,
                                                  const int* __restrict__ rowptr,
                                                  const float* __restrict__ dinv,
                                                  unsigned* __restrict__ csr_ew,
                                                  int nrows, int e, int chunk, int n,
                                                  int ngemm, int nfill) {
    __shared__ __align__(16) unsigned short sB[128 * LDK];

    int mn2 = (ngemm < nfill ? ngemm : nfill) * 2;
    bool isg;
    int bid;
    if ((int)blockIdx.x < mn2) {
        isg = (blockIdx.x & 1) == 0;
        bid = blockIdx.x >> 1;
    } else {
        int r = (int)blockIdx.x - mn2;
        isg = ngemm > nfill;
        bid = (mn2 >> 1) + r;
    }

    if (!isg) {
        // ---- CSR fill: slot = rowptr[d] + pref[c][d] + pos[i]; atomic-free ----
        int base = (bid * 256 + (int)threadIdx.x) * 4;
        if (base >= e) return;
        const unsigned short* pr = pref + (size_t)(base / chunk) * n;  // chunk%4==0
        if (base + 3 < e && (((size_t)src & 15) == 0) && (((size_t)dst & 15) == 0)) {
            int4 s4 = *(const int4*)(src + base);
            int4 d4 = *(const int4*)(dst + base);
            ushort4 p4 = *(const ushort4*)(pos + base);
            float as0 = dinv[s4.x], as1 = dinv[s4.y], as2 = dinv[s4.z], as3 = dinv[s4.w];
            float ad0 = dinv[d4.x], ad1 = dinv[d4.y], ad2 = dinv[d4.z], ad3 = dinv[d4.w];
            int b0 = rowptr[d4.x] + pr[d4.x] + p4.x;
            int b1 = rowptr[d4.y] + pr[d4.y] + p4.y;
            int b2 = rowptr[d4.z] + pr[d4.z] + p4.z;
            int b3 = rowptr[d4.w] + pr[d4.w] + p4.w;
            csr_ew[b0] = ((unsigned)s4.x << 16) | (unsigned)f2bf(as0 * ad0);
            csr_ew[b1] = ((unsigned)s4.y << 16) | (unsigned)f2bf(as1 * ad1);
            csr_ew[b2] = ((unsigned)s4.z << 16) | (unsigned)f2bf(as2 * ad2);
            csr_ew[b3] = ((unsigned)s4.w << 16) | (unsigned)f2bf(as3 * ad3);
        } else {
            for (int i = base; i < e && i < base + 4; ++i) {
                int s = src[i], d = dst[i];
                float w = dinv[s] * dinv[d];
                csr_ew[rowptr[d] + (int)pr[d] + (int)pos[i]] =
                    ((unsigned)s << 16) | (unsigned)f2bf(w);
            }
        }
        return;
    }

    // ---- lean GEMM: B in LDS, A per-lane from global ----
    const int t = threadIdx.x;
    const int row0 = bid * 64;

    for (int idx = t; idx < 128 * 16; idx += 256) {
        int c = idx >> 4, ch = idx & 15;
        uint4 v = ((const uint4*)(Wt + c * 128))[ch];
        *(uint4*)(&sB[c * LDK + ch * 8]) = v;
    }

    const int w = t >> 6;
    const int lane = t & 63;
    const int m = lane & 15;
    const int quad = lane >> 4;

    const int grow_a = row0 + w * 16 + m;
    const int srow = grow_a < nrows ? grow_a : 0;
    const float4* Xr = (const float4*)(X + (size_t)srow * 128);
    short8 a[4];
    #pragma unroll
    for (int ks = 0; ks < 4; ++ks) {
        int ko4 = ks * 8 + quad * 2;
        float4 v0 = Xr[ko4];
        float4 v1 = Xr[ko4 + 1];
        short8 av;
        av[0] = (short)f2bf(v0.x); av[1] = (short)f2bf(v0.y);
        av[2] = (short)f2bf(v0.z); av[3] = (short)f2bf(v0.w);
        av[4] = (short)f2bf(v1.x); av[5] = (short)f2bf(v1.y);
        av[6] = (short)f2bf(v1.z); av[7] = (short)f2bf(v1.w);
        a[ks] = av;
    }
    __syncthreads();

    f32x4 acc[8] = {};
    #pragma unroll
    for (int ks = 0; ks < 4; ++ks) {
        int ko = ks * 32 + quad * 8;
        #pragma unroll
        for (int ct = 0; ct < 8; ++ct) {
            short8 b = *(const short8*)(&sB[(ct * 16 + m) * LDK + ko]);
            acc[ct] = __builtin_amdgcn_mfma_f32_16x16x32_bf16(a[ks], b, acc[ct], 0, 0, 0);
        }
    }
    #pragma unroll
    for (int r = 0; r < 4; ++r) {
        int grow = row0 + w * 16 + quad * 4 + r;
        if (grow >= nrows) continue;
        unsigned short* yr = Y + (size_t)grow * 128 + m;
        #pragma unroll
        for (int ct = 0; ct < 8; ++ct) yr[ct * 16] = f2bf(acc[ct][r]);
    }
}

// ---------------- per-block GraphNorm finalize into LDS (helper) ----------------
__device__ __forceinline__ void finstats_lds(const float* __restrict__ pS,
                                             const float* __restrict__ pQ,
                                             const float* __restrict__ gw,
                                             const float* __restrict__ gb,
                                             const float* __restrict__ ga,
                                             float* __restrict__ sCS,
                                             float* __restrict__ sCB, int n) {
    int c = threadIdx.x;
    if (c < 128) {
        float s = 0.f, q = 0.f;
        #pragma unroll 8
        for (int blk = 0; blk < 64; ++blk) {
            s += pS[blk * 128 + c];
            q += pQ[blk * 128 + c];
        }
        float inv_n = 1.0f / (float)n;
        float m = s * inv_n;
        float eh2 = q * inv_n;
        float a = ga[c];
        float var = eh2 - (2.0f * a - a * a) * m * m;
        float scale = rsqrtf(var + GN_EPS) * gw[c];
        sCS[c] = scale;
        sCB[c] = gb[c] - a * m * scale;
    }
}

// ---------------- MFMA GEMM (bf16 + per-block GraphNorm finalize + affine + ReLU) ----------------
__global__ __launch_bounds__(256) void k_gemm_bf(const unsigned short* __restrict__ Xb,
                                                 const unsigned short* __restrict__ Wt,
                                                 unsigned short* __restrict__ Y,
                                                 const float* __restrict__ pS,
                                                 const float* __restrict__ pQ,
                                                 const float* __restrict__ gw,
                                                 const float* __restrict__ gb,
                                                 const float* __restrict__ ga,
                                                 int nrows, int n) {
    __shared__ __align__(16) unsigned short sB[128 * LDK];
    __shared__ __align__(16) float sCS[128];
    __shared__ __align__(16) float sCB[128];
    const int t = threadIdx.x;
    const int row0 = blockIdx.x * 64;

    finstats_lds(pS, pQ, gw, gb, ga, sCS, sCB, n);
    for (int idx = t; idx < 128 * 16; idx += 256) {
        int c = idx >> 4, ch = idx & 15;
        uint4 v = ((const uint4*)(Wt + c * 128))[ch];
        *(uint4*)(&sB[c * LDK + ch * 8]) = v;
    }
    __syncthreads();

    const int w = t >> 6;
    const int lane = t & 63;
    const int m = lane & 15;
    const int quad = lane >> 4;

    const int grow_a = row0 + w * 16 + m;
    const int srow = grow_a < nrows ? grow_a : 0;
    const uint4* Xr = (const uint4*)(Xb + (size_t)srow * 128);
    short8 a[4];
    #pragma unroll
    for (int ks = 0; ks < 4; ++ks) {
        uint4 u = Xr[ks * 4 + quad];
        int kf = (ks * 32 + quad * 8) >> 2;
        float4 s0 = ((const float4*)sCS)[kf];
        float4 s1 = ((const float4*)sCS)[kf + 1];
        float4 c0 = ((const float4*)sCB)[kf];
        float4 c1 = ((const float4*)sCB)[kf + 1];
        short8 av;
        av[0] = (short)f2bf(fmaxf(fmaf(bflo(u.x), s0.x, c0.x), 0.f));
        av[1] = (short)f2bf(fmaxf(fmaf(bfhi(u.x), s0.y, c0.y), 0.f));
        av[2] = (short)f2bf(fmaxf(fmaf(bflo(u.y), s0.z, c0.z), 0.f));
        av[3] = (short)f2bf(fmaxf(fmaf(bfhi(u.y), s0.w, c0.w), 0.f));
        av[4] = (short)f2bf(fmaxf(fmaf(bflo(u.z), s1.x, c1.x), 0.f));
        av[5] = (short)f2bf(fmaxf(fmaf(bfhi(u.z), s1.y, c1.y), 0.f));
        av[6] = (short)f2bf(fmaxf(fmaf(bflo(u.w), s1.z, c1.z), 0.f));
        av[7] = (short)f2bf(fmaxf(fmaf(bfhi(u.w), s1.w, c1.w), 0.f));
        a[ks] = av;
    }

    f32x4 acc[8] = {};
    #pragma unroll
    for (int ks = 0; ks < 4; ++ks) {
        int ko = ks * 32 + quad * 8;
        #pragma unroll
        for (int ct = 0; ct < 8; ++ct) {
            short8 b = *(const short8*)(&sB[(ct * 16 + m) * LDK + ko]);
            acc[ct] = __builtin_amdgcn_mfma_f32_16x16x32_bf16(a[ks], b, acc[ct], 0, 0, 0);
        }
    }
    #pragma unroll
    for (int r = 0; r < 4; ++r) {
        int grow = row0 + w * 16 + quad * 4 + r;
        if (grow >= nrows) continue;
        unsigned short* yr = Y + (size_t)grow * 128 + m;
        #pragma unroll
        for (int ct = 0; ct < 8; ++ct) yr[ct * 16] = f2bf(acc[ct][r]);
    }
}

// ---------------- pull-gather conv + fused GraphNorm stats ----------------
__global__ __launch_bounds__(256) void k_gather(const unsigned short* __restrict__ H,
                                                unsigned short* __restrict__ O,
                                                const int* __restrict__ rowptr,
                                                const unsigned* __restrict__ csr_ew,
                                                const float* __restrict__ dinv,
                                                const float* __restrict__ bias,
                                                float* __restrict__ pS,
                                                float* __restrict__ pQ, int n) {
    __shared__ float sS[4][128];
    __shared__ float sQ[4][128];
    const int wid = threadIdx.x >> 6;
    const int node = blockIdx.x * 4 + wid;
    const int lane = threadIdx.x & 63;
    const int qw = lane >> 4;
    const int ql = lane & 15;
    const uint4* Hx = (const uint4*)H;
    float acc[8] = {};
    if (node < n) {
        float di = dinv[node];
        if (qw == 0) {
            uint4 u = Hx[(size_t)node * 16 + ql];
            float dd = di * di;
            float4 ba = ((const float4*)bias)[ql * 2];
            float4 bb = ((const float4*)bias)[ql * 2 + 1];
            acc[0] = bflo(u.x) * dd + ba.x; acc[1] = bfhi(u.x) * dd + ba.y;
            acc[2] = bflo(u.y) * dd + ba.z; acc[3] = bfhi(u.y) * dd + ba.w;
            acc[4] = bflo(u.z) * dd + bb.x; acc[5] = bfhi(u.z) * dd + bb.y;
            acc[6] = bflo(u.w) * dd + bb.z; acc[7] = bfhi(u.w) * dd + bb.w;
        }
        int j = rowptr[node];
        const int end = rowptr[node + 1];
        for (; j + 16 <= end; j += 16) {
            unsigned ew[4];
            #pragma unroll
            for (int q = 0; q < 4; ++q) ew[q] = csr_ew[j + 4 * q + qw];
            uint4 u[4];
            #pragma unroll
            for (int q = 0; q < 4; ++q)
                u[q] = Hx[((ew[q] >> 12) & 0xFFFF0u) + (unsigned)ql];
            #pragma unroll
            for (int q = 0; q < 4; ++q) {
                float nr = __uint_as_float(ew[q] << 16);
                acc[0] += bflo(u[q].x) * nr; acc[1] += bfhi(u[q].x) * nr;
                acc[2] += bflo(u[q].y) * nr; acc[3] += bfhi(u[q].y) * nr;
                acc[4] += bflo(u[q].z) * nr; acc[5] += bfhi(u[q].z) * nr;
                acc[6] += bflo(u[q].w) * nr; acc[7] += bfhi(u[q].w) * nr;
            }
        }
        if (j < end) {   // exactly 8 remain: 2 edges per quarter-wave
            unsigned ew[2];
            #pragma unroll
            for (int q = 0; q < 2; ++q) ew[q] = csr_ew[j + qw * 2 + q];
            uint4 u[2];
            #pragma unroll
            for (int q = 0; q < 2; ++q)
                u[q] = Hx[((ew[q] >> 12) & 0xFFFF0u) + (unsigned)ql];
            #pragma unroll
            for (int q = 0; q < 2; ++q) {
                float nr = __uint_as_float(ew[q] << 16);
                acc[0] += bflo(u[q].x) * nr; acc[1] += bfhi(u[q].x) * nr;
                acc[2] += bflo(u[q].y) * nr; acc[3] += bfhi(u[q].y) * nr;
                acc[4] += bflo(u[q].z) * nr; acc[5] += bfhi(u[q].z) * nr;
                acc[6] += bflo(u[q].w) * nr; acc[7] += bfhi(u[q].w) * nr;
            }
        }
        #pragma unroll
        for (int i = 0; i < 8; ++i) {
            acc[i] += __shfl_down(acc[i], 32);
            acc[i] += __shfl_down(acc[i], 16);
        }
    }
    if (qw == 0) {
        if (node < n) {
            unsigned short h[8];
            float v[8];
            #pragma unroll
            for (int i = 0; i < 8; ++i) {
                h[i] = f2bf(acc[i]);
                v[i] = __uint_as_float((unsigned)h[i] << 16);
                sS[wid][ql * 8 + i] = v[i];
                sQ[wid][ql * 8 + i] = v[i] * v[i];
            }
            uint4 o;
            o.x = (unsigned)h[0] | ((unsigned)h[1] << 16);
            o.y = (unsigned)h[2] | ((unsigned)h[3] << 16);
            o.z = (unsigned)h[4] | ((unsigned)h[5] << 16);
            o.w = (unsigned)h[6] | ((unsigned)h[7] << 16);
            *(uint4*)(O + (size_t)node * 128 + ql * 8) = o;
        } else {
            #pragma unroll
            for (int i = 0; i < 8; ++i) {
                sS[wid][ql * 8 + i] = 0.f;
                sQ[wid][ql * 8 + i] = 0.f;
            }
        }
    }
    __syncthreads();
    const int t = threadIdx.x;
    if (t < 128) {
        float s = sS[0][t] + sS[1][t] + sS[2][t] + sS[3][t];
        float q = sQ[0][t] + sQ[1][t] + sQ[2][t] + sQ[3][t];
        const int slotb = (blockIdx.x & 63) << 7;
        atomicAdd(&pS[slotb + t], s);
        atomicAdd(&pQ[slotb + t], q);
    }
}

// ---------------- Z = relu(affine(bufG)) @ M  (64 nodes/block, fused finalize) ----------------
__global__ __launch_bounds__(256) void k_zproj(const unsigned short* __restrict__ Xb,
                                               const float* __restrict__ M,
                                               const float* __restrict__ pS,
                                               const float* __restrict__ pQ,
                                               const float* __restrict__ gw,
                                               const float* __restrict__ gb,
                                               const float* __restrict__ ga,
                                               float2* __restrict__ Z, int n) {
    __shared__ __align__(16) float sCS[128];
    __shared__ __align__(16) float sCB[128];
    __shared__ __align__(16) float sM[256];
    finstats_lds(pS, pQ, gw, gb, ga, sCS, sCB, n);
    if (threadIdx.x < 128) {
        sM[threadIdx.x * 2] = M[threadIdx.x * 2];
        sM[threadIdx.x * 2 + 1] = M[threadIdx.x * 2 + 1];
    }
    __syncthreads();

    const int wid = threadIdx.x >> 6;
    const int lane = threadIdx.x & 63;   // cols 2*lane, 2*lane+1
    const int c0 = lane * 2;
    const float cs0 = sCS[c0], cs1 = sCS[c0 + 1];
    const float cb0 = sCB[c0], cb1 = sCB[c0 + 1];
    const float m00 = sM[c0 * 2], m01 = sM[c0 * 2 + 1];
    const float m10 = sM[(c0 + 1) * 2], m11 = sM[(c0 + 1) * 2 + 1];

    #pragma unroll
    for (int p = 0; p < 16; ++p) {
        int node = (int)blockIdx.x * 64 + p * 4 + wid;
        if (node >= n) break;
        unsigned u = ((const unsigned*)Xb)[(size_t)node * 64 + lane];
        float a = fmaxf(fmaf(bflo(u), cs0, cb0), 0.f);
        float b = fmaxf(fmaf(bfhi(u), cs1, cb1), 0.f);
        float p0 = a * m00 + b * m10;
        float p1 = a * m01 + b * m11;
        #pragma unroll
        for (int off = 32; off; off >>= 1) {
            p0 += __shfl_down(p0, off);
            p1 += __shfl_down(p1, off);
        }
        if (lane == 0) Z[node] = make_float2(p0, p1);
    }
}

// ---------------- final: out[i] = dinv[i]^2*Z[i] + sum w*Z[s] + mb ----------------
__global__ __launch_bounds__(256) void k_gatherZ(const float2* __restrict__ Z,
                                                 const int* __restrict__ rowptr,
                                                 const unsigned* __restrict__ csr_ew,
                                                 const float* __restrict__ dinv,
                                                 const float* __restrict__ mb,
                                                 float* __restrict__ out, int n) {
    int wid = threadIdx.x >> 6;
    int lane = threadIdx.x & 63;
    int g = lane >> 4;
    int gl = lane & 15;
    int node = blockIdx.x * 16 + wid * 4 + g;
    if (node >= n) return;
    float2 acc = make_float2(0.f, 0.f);
    if (gl == 0) {
        float di = dinv[node];
        float2 z = Z[node];
        acc.x = z.x * di * di + mb[0];
        acc.y = z.y * di * di + mb[1];
    }
    int j = rowptr[node];
    const int end = rowptr[node + 1];
    for (int jj = j + gl; jj < end; jj += 16) {
        unsigned ew = csr_ew[jj];
        float2 z = Z[ew >> 16];
        float w = __uint_as_float(ew << 16);
        acc.x += z.x * w;
        acc.y += z.y * w;
    }
    #pragma unroll
    for (int off = 8; off; off >>= 1) {
        acc.x += __shfl_down(acc.x, off);
        acc.y += __shfl_down(acc.y, off);
    }
    if (gl == 0) {
        out[(size_t)node * 2]     = acc.x;
        out[(size_t)node * 2 + 1] = acc.y;
    }
}

extern "C" void kernel_launch(void* const* d_in, const int* in_sizes, int n_in,
                              void* d_out, int out_size, void* d_ws, size_t ws_size,
                              hipStream_t stream) {
    const float* x    = (const float*)d_in[0];
    const int*   ei   = (const int*)  d_in[1];
    const float* W1   = (const float*)d_in[2];
    const float* b1   = (const float*)d_in[3];
    const float* W2   = (const float*)d_in[4];
    const float* b2   = (const float*)d_in[5];
    const float* W3   = (const float*)d_in[6];
    const float* b3   = (const float*)d_in[7];
    const float* gn1w = (const float*)d_in[8];
    const float* gn1b = (const float*)d_in[9];
    const float* gn1a = (const float*)d_in[10];
    const float* gn2w = (const float*)d_in[11];
    const float* gn2b = (const float*)d_in[12];
    const float* gn2a = (const float*)d_in[13];
    const float* Wout = (const float*)d_in[14];
    const float* bout = (const float*)d_in[15];
    float* out = (float*)d_out;

    const int n = in_sizes[0] / 128;
    const int e = in_sizes[1] / 2;
    const int* srcI = ei;
    const int* dstI = ei + e;

    // chunking for the histogram CSR build (chunk forced to multiple of 4)
    const int chunk = (((e + HIST_C - 1) / HIST_C) + 3) & ~3;
    const int nchunks = (e + chunk - 1) / chunk;

    // bump allocator, 16B-aligned blocks; everything is explicitly initialized
    // by kernels (no memset dispatch).
    char* base = (char*)d_ws;
    size_t off = 0;
    auto take = [&](size_t bytes) -> void* {
        void* r = base + off;
        off += (bytes + 15) & ~(size_t)15;
        return r;
    };
    unsigned short* bufH = (unsigned short*)take((size_t)n * 256);   // n*128 bf16
    unsigned short* bufG = (unsigned short*)take((size_t)n * 256);   // n*128 bf16
    float* dinv     = (float*)take((size_t)n * 4);
    int*   rowptr   = (int*)take(((size_t)n + 1) * 4);
    int*   partial  = (int*)take(256 * 4);              // per-256-node padded partials
    unsigned short* Wt = (unsigned short*)take(2 * 16384 * 2);
    float* M        = (float*)take(256 * 4);
    float* mb       = (float*)take(2 * 4);
    float2* Z       = (float2*)take((size_t)n * 8);
    int*   degi     = (int*)take((size_t)n * 4);
    unsigned short* cnt = (unsigned short*)take((size_t)nchunks * n * 2);
    unsigned short* pos = (unsigned short*)take((size_t)e * 2);
    float* pS       = (float*)take(2 * 64 * 128 * 4);   // layer1 [0,8192), layer2 [8192,16384)
    float* pQ       = (float*)take(2 * 64 * 128 * 4);
    size_t csr_cap  = (size_t)e + 8 * (size_t)n;        // pad-8 worst case
    unsigned* csr_ew = (unsigned*)take(csr_cap * 4);

    const int nb = (n + SCAN_CHUNK - 1) / SCAN_CHUNK;
    const int gemmGrid = (n + 63) / 64;
    const int fillGrid = (e + 1023) / 1024;             // 4 edges/thread
    const int gathGrid = (n + 3) / 4;

    // ---- CSR build (atomic-free) + weight prep + pS/pQ zero ----
    k_prep_hist<<<3 + nchunks, 256, 0, stream>>>(W1, W2, W3, Wout, b3, bout,
                                                 Wt, M, mb, pS, pQ, dstI, cnt, pos,
                                                 e, n, chunk);
    k_reduce<<<(n + 255) / 256, 256, 0, stream>>>(cnt, degi, partial, n, nchunks);
    k_scanfinal<<<nb, 256, 0, stream>>>(degi, partial, rowptr, dinv, csr_ew, n, nb);

    // ---- CSR fill (independent) fused with layer-1 GEMM ----
    k_fillgemm<<<gemmGrid + fillGrid, 256, 0, stream>>>(x, Wt, bufH, srcI, dstI,
                                                        pos, cnt, rowptr, dinv, csr_ew,
                                                        n, e, chunk, n, gemmGrid, fillGrid);
    // layer 1 aggregate + stats
    k_gather<<<gathGrid, 256, 0, stream>>>(bufH, bufG, rowptr, csr_ew, dinv, b1, pS, pQ, n);

    // layer 2 (per-block GraphNorm-1 finalize inside)
    k_gemm_bf<<<gemmGrid, 256, 0, stream>>>(bufG, Wt + 16384, bufH, pS, pQ,
                                            gn1w, gn1b, gn1a, n, n);
    k_gather<<<gathGrid, 256, 0, stream>>>(bufH, bufG, rowptr, csr_ew, dinv, b2,
                                           pS + 8192, pQ + 8192, n);

    // layer 3 collapsed (per-block GraphNorm-2 finalize inside zproj)
    k_zproj<<<(n + 63) / 64, 256, 0, stream>>>(bufG, M, pS + 8192, pQ + 8192,
                                               gn2w, gn2b, gn2a, Z, n);
    k_gatherZ<<<(n + 15) / 16, 256, 0, stream>>>(Z, rowptr, csr_ew, dinv, mb, out, n);
}

// Round 8
// 265.428 us; speedup vs baseline: 1.0194x; 1.0194x over previous
//
#include <hip/hip_runtime.h>

#define GN_EPS 1e-5f

// NOTE: node ids packed as (src<<16)|bf16(weight) in csr_ew; requires n < 65536.
// CSR rows are PADDED to multiples of 8 with zero entries (src 0, weight 0.0).
// CSR build is ATOMIC-FREE (global): per-chunk LDS histogram with packed u16
// counters gives degree counts AND per-edge within-chunk slots; a prefix pass
// over the per-chunk count table gives global slots.
// GEMMs stage only B (W^T) in LDS (A has no cross-wave reuse).
// GraphNorm finalize is a separate tiny dispatch: in-kernel grid signaling via
// __threadfence costs an L2 writeback PER BLOCK on multi-XCD CDNA4 (R5: 4-30x
// kernel slowdown). Do NOT re-fuse.
// Gather main loop keeps 6 row-reads in flight per quarter-wave (24 edges/iter)
// to probe/exploit L3 latency-bound behavior (R8 experiment).

#define HIST_C 64
#define SCAN_CHUNK 4096
#define LDK 136

typedef __attribute__((ext_vector_type(8))) short short8;
typedef __attribute__((ext_vector_type(4))) float f32x4;

__device__ __forceinline__ unsigned short f2bf(float f) {
    unsigned u = __float_as_uint(f);
    u += 0x7fffu + ((u >> 16) & 1u);   // round-to-nearest-even
    return (unsigned short)(u >> 16);
}
__device__ __forceinline__ float bflo(unsigned u) { return __uint_as_float(u << 16); }
__device__ __forceinline__ float bfhi(unsigned u) { return __uint_as_float(u & 0xffff0000u); }

// ---------------- fused weight prep + LDS-histogram degree count ----------------
__global__ __launch_bounds__(256) void k_prep_hist(const float* __restrict__ W1,
                                                   const float* __restrict__ W2,
                                                   const float* __restrict__ W3,
                                                   const float* __restrict__ Wo,
                                                   const float* __restrict__ b3,
                                                   const float* __restrict__ bo,
                                                   unsigned short* __restrict__ Wt,
                                                   float* __restrict__ M,
                                                   float* __restrict__ mb,
                                                   const int* __restrict__ dst,
                                                   unsigned short* __restrict__ cnt,
                                                   unsigned short* __restrict__ pos,
                                                   int e, int n, int chunk) {
    __shared__ __align__(16) unsigned bins[32768];   // 128 KB: 2 u16 counters / u32
    if (blockIdx.x < 2) {
        unsigned short* sT = (unsigned short*)bins;  // 128*130 u16 alias
        const float* W = blockIdx.x == 0 ? W1 : W2;
        unsigned short* o = Wt + blockIdx.x * 16384;
        const float4* W4 = (const float4*)W;
        for (int idx = threadIdx.x; idx < 128 * 32; idx += 256) {
            int k = idx >> 5, c4 = idx & 31;
            float4 v = W4[k * 32 + c4];
            sT[(c4 * 4 + 0) * 130 + k] = f2bf(v.x);
            sT[(c4 * 4 + 1) * 130 + k] = f2bf(v.y);
            sT[(c4 * 4 + 2) * 130 + k] = f2bf(v.z);
            sT[(c4 * 4 + 3) * 130 + k] = f2bf(v.w);
        }
        __syncthreads();
        for (int idx = threadIdx.x; idx < 128 * 128; idx += 256) {
            int c = idx >> 7, k = idx & 127;
            o[idx] = sT[c * 130 + k];
        }
    } else if (blockIdx.x == 2) {
        int k = threadIdx.x;
        if (k < 128) {
            float m0 = 0.f, m1 = 0.f;
            for (int c = 0; c < 128; ++c) {
                float w = W3[k * 128 + c];
                m0 += w * Wo[c * 2];
                m1 += w * Wo[c * 2 + 1];
            }
            M[k * 2] = m0;
            M[k * 2 + 1] = m1;
            if (k < 2) {
                float s = 0.f;
                for (int c = 0; c < 128; ++c) s += b3[c] * Wo[c * 2 + k];
                mb[k] = s + bo[k];
            }
        }
    } else {
        const int c = (int)blockIdx.x - 3;
        const int c0 = c * chunk;
        const int c1 = (c0 + chunk < e) ? c0 + chunk : e;
        const int nw = (n + 1) >> 1;
        for (int i = threadIdx.x; i < nw; i += 256) bins[i] = 0u;
        __syncthreads();
        const bool al = ((size_t)dst & 15) == 0;
        for (int i = c0 + (int)threadIdx.x * 4; i < c1; i += 1024) {
            if (al && i + 3 < c1) {
                int4 d4 = *(const int4*)(dst + i);
                unsigned o0 = atomicAdd(&bins[(unsigned)d4.x >> 1],
                                        (d4.x & 1) ? 0x10000u : 1u);
                unsigned o1 = atomicAdd(&bins[(unsigned)d4.y >> 1],
                                        (d4.y & 1) ? 0x10000u : 1u);
                unsigned o2 = atomicAdd(&bins[(unsigned)d4.z >> 1],
                                        (d4.z & 1) ? 0x10000u : 1u);
                unsigned o3 = atomicAdd(&bins[(unsigned)d4.w >> 1],
                                        (d4.w & 1) ? 0x10000u : 1u);
                ushort4 p;
                p.x = (unsigned short)((o0 >> ((d4.x & 1) * 16)) & 0xffffu);
                p.y = (unsigned short)((o1 >> ((d4.y & 1) * 16)) & 0xffffu);
                p.z = (unsigned short)((o2 >> ((d4.z & 1) * 16)) & 0xffffu);
                p.w = (unsigned short)((o3 >> ((d4.w & 1) * 16)) & 0xffffu);
                *(ushort4*)(pos + i) = p;
            } else {
                for (int k = i; k < c1 && k < i + 4; ++k) {
                    int d = dst[k];
                    unsigned old = atomicAdd(&bins[(unsigned)d >> 1],
                                             (d & 1) ? 0x10000u : 1u);
                    pos[k] = (unsigned short)((old >> ((d & 1) * 16)) & 0xffffu);
                }
            }
        }
        __syncthreads();
        unsigned short* cr = cnt + (size_t)c * n;
        if ((n & 1) == 0) {
            unsigned* cr32 = (unsigned*)cr;
            for (int i = threadIdx.x; i < (n >> 1); i += 256) cr32[i] = bins[i];
        } else {
            for (int i = threadIdx.x; i < n; i += 256)
                cr[i] = (unsigned short)((bins[i >> 1] >> ((i & 1) * 16)) & 0xffffu);
        }
    }
}

// ---------------- cross-chunk prefix + degree + per-256-node padded partials ----------------
__global__ __launch_bounds__(256) void k_reduce(unsigned short* __restrict__ cnt,
                                                int* __restrict__ degi,
                                                int* __restrict__ partial,
                                                int n, int nchunks) {
    int node = blockIdx.x * 256 + threadIdx.x;
    int pdeg = 0;
    if (node < n) {
        int s = 0;
        int cb = 0;
        for (; cb + 8 <= nchunks; cb += 8) {
            int v[8];
            #pragma unroll
            for (int q = 0; q < 8; ++q) v[q] = cnt[(size_t)(cb + q) * n + node];
            #pragma unroll
            for (int q = 0; q < 8; ++q) {
                cnt[(size_t)(cb + q) * n + node] = (unsigned short)s;
                s += v[q];
            }
        }
        for (; cb < nchunks; ++cb) {
            size_t id = (size_t)cb * n + node;
            int v = cnt[id];
            cnt[id] = (unsigned short)s;
            s += v;
        }
        degi[node] = s;
        pdeg = (s + 7) & ~7;
    }
    #pragma unroll
    for (int off = 32; off; off >>= 1) pdeg += __shfl_down(pdeg, off);
    __shared__ int ws[4];
    if ((threadIdx.x & 63) == 0) ws[threadIdx.x >> 6] = pdeg;
    __syncthreads();
    if (threadIdx.x == 0) partial[blockIdx.x] = ws[0] + ws[1] + ws[2] + ws[3];
}

// block b: base = sum(partial[0..b*16-1]) computed locally (<=192 L2-hot loads)
__global__ __launch_bounds__(256) void k_scanfinal(const int* __restrict__ degi,
                                                   const int* __restrict__ partial,
                                                   int* __restrict__ rowptr,
                                                   float* __restrict__ dinv, int n, int nb) {
    int blockbase = 0;
    for (int i = 0; i < (int)blockIdx.x * 16; ++i) blockbase += partial[i];

    int base = blockIdx.x * SCAN_CHUNK + threadIdx.x * 16;
    int v[16], pv[16];
    int s = 0;
    #pragma unroll
    for (int q = 0; q < 16; ++q) {
        int i = base + q;
        v[q] = (i < n) ? degi[i] : 0;
        pv[q] = (v[q] + 7) & ~7;
        s += pv[q];
    }
    const int lane = threadIdx.x & 63;
    const int wid = threadIdx.x >> 6;
    int x = s;
    #pragma unroll
    for (int off = 1; off < 64; off <<= 1) {
        int t = __shfl_up(x, off);
        if (lane >= off) x += t;
    }
    __shared__ int ws[4];
    if (lane == 63) ws[wid] = x;
    __syncthreads();
    int waveoff = 0;
    if (wid > 0) waveoff += ws[0];
    if (wid > 1) waveoff += ws[1];
    if (wid > 2) waveoff += ws[2];
    int excl = x - s + waveoff + blockbase;
    #pragma unroll
    for (int q = 0; q < 16; ++q) {
        int i = base + q;
        if (i < n) {
            rowptr[i] = excl;
            dinv[i] = rsqrtf((float)(v[q] + 1));
        }
        excl += pv[q];
    }
    if ((int)blockIdx.x == nb - 1 && threadIdx.x == 255) {
        rowptr[n] = excl;
    }
}

// fill: slot = rowptr[d] + pref[c][d] + pos[i]; atomic-free, 4 edges/thread
__global__ void k_fill(const int* __restrict__ src, const int* __restrict__ dst,
                       const unsigned short* __restrict__ pos,
                       const unsigned short* __restrict__ pref,
                       const int* __restrict__ rowptr,
                       const float* __restrict__ dinv,
                       unsigned* __restrict__ csr_ew, int e, int n, int chunk) {
    int base = (blockIdx.x * blockDim.x + threadIdx.x) * 4;
    if (base >= e) return;
    const unsigned short* pr = pref + (size_t)(base / chunk) * n;  // chunk%4==0
    if (base + 3 < e && (((size_t)src & 15) == 0) && (((size_t)dst & 15) == 0)) {
        int4 s4 = *(const int4*)(src + base);
        int4 d4 = *(const int4*)(dst + base);
        ushort4 p4 = *(const ushort4*)(pos + base);
        float as0 = dinv[s4.x], as1 = dinv[s4.y], as2 = dinv[s4.z], as3 = dinv[s4.w];
        float ad0 = dinv[d4.x], ad1 = dinv[d4.y], ad2 = dinv[d4.z], ad3 = dinv[d4.w];
        int b0 = rowptr[d4.x] + pr[d4.x] + p4.x;
        int b1 = rowptr[d4.y] + pr[d4.y] + p4.y;
        int b2 = rowptr[d4.z] + pr[d4.z] + p4.z;
        int b3 = rowptr[d4.w] + pr[d4.w] + p4.w;
        csr_ew[b0] = ((unsigned)s4.x << 16) | (unsigned)f2bf(as0 * ad0);
        csr_ew[b1] = ((unsigned)s4.y << 16) | (unsigned)f2bf(as1 * ad1);
        csr_ew[b2] = ((unsigned)s4.z << 16) | (unsigned)f2bf(as2 * ad2);
        csr_ew[b3] = ((unsigned)s4.w << 16) | (unsigned)f2bf(as3 * ad3);
    } else {
        for (int i = base; i < e && i < base + 4; ++i) {
            int s = src[i], d = dst[i];
            float w = dinv[s] * dinv[d];
            csr_ew[rowptr[d] + (int)pr[d] + (int)pos[i]] =
                ((unsigned)s << 16) | (unsigned)f2bf(w);
        }
    }
}

// ---------------- MFMA GEMM (fp32 input, layer 1): B in LDS, A per-lane ----------------
__global__ __launch_bounds__(256) void k_gemm_f32(const float* __restrict__ X,
                                                  const unsigned short* __restrict__ Wt,
                                                  unsigned short* __restrict__ Y,
                                                  int nrows) {
    __shared__ __align__(16) unsigned short sB[128 * LDK];
    const int t = threadIdx.x;
    const int row0 = blockIdx.x * 64;

    for (int idx = t; idx < 128 * 16; idx += 256) {
        int c = idx >> 4, ch = idx & 15;
        uint4 v = ((const uint4*)(Wt + c * 128))[ch];
        *(uint4*)(&sB[c * LDK + ch * 8]) = v;
    }

    const int w = t >> 6;
    const int lane = t & 63;
    const int m = lane & 15;
    const int quad = lane >> 4;

    const int grow_a = row0 + w * 16 + m;
    const int srow = grow_a < nrows ? grow_a : 0;
    const float4* Xr = (const float4*)(X + (size_t)srow * 128);
    short8 a[4];
    #pragma unroll
    for (int ks = 0; ks < 4; ++ks) {
        int ko4 = ks * 8 + quad * 2;
        float4 v0 = Xr[ko4];
        float4 v1 = Xr[ko4 + 1];
        short8 av;
        av[0] = (short)f2bf(v0.x); av[1] = (short)f2bf(v0.y);
        av[2] = (short)f2bf(v0.z); av[3] = (short)f2bf(v0.w);
        av[4] = (short)f2bf(v1.x); av[5] = (short)f2bf(v1.y);
        av[6] = (short)f2bf(v1.z); av[7] = (short)f2bf(v1.w);
        a[ks] = av;
    }
    __syncthreads();

    f32x4 acc[8] = {};
    #pragma unroll
    for (int ks = 0; ks < 4; ++ks) {
        int ko = ks * 32 + quad * 8;
        #pragma unroll
        for (int ct = 0; ct < 8; ++ct) {
            short8 b = *(const short8*)(&sB[(ct * 16 + m) * LDK + ko]);
            acc[ct] = __builtin_amdgcn_mfma_f32_16x16x32_bf16(a[ks], b, acc[ct], 0, 0, 0);
        }
    }
    #pragma unroll
    for (int r = 0; r < 4; ++r) {
        int grow = row0 + w * 16 + quad * 4 + r;
        if (grow >= nrows) continue;
        unsigned short* yr = Y + (size_t)grow * 128 + m;
        #pragma unroll
        for (int ct = 0; ct < 8; ++ct) yr[ct * 16] = f2bf(acc[ct][r]);
    }
}

// ---------------- MFMA GEMM (bf16 + fused GraphNorm affine + ReLU): B in LDS ----------------
__global__ __launch_bounds__(256) void k_gemm_bf(const unsigned short* __restrict__ Xb,
                                                 const unsigned short* __restrict__ Wt,
                                                 unsigned short* __restrict__ Y,
                                                 const float* __restrict__ cs,
                                                 const float* __restrict__ cb,
                                                 int nrows) {
    __shared__ __align__(16) unsigned short sB[128 * LDK];
    const int t = threadIdx.x;
    const int row0 = blockIdx.x * 64;

    for (int idx = t; idx < 128 * 16; idx += 256) {
        int c = idx >> 4, ch = idx & 15;
        uint4 v = ((const uint4*)(Wt + c * 128))[ch];
        *(uint4*)(&sB[c * LDK + ch * 8]) = v;
    }

    const int w = t >> 6;
    const int lane = t & 63;
    const int m = lane & 15;
    const int quad = lane >> 4;

    const int grow_a = row0 + w * 16 + m;
    const int srow = grow_a < nrows ? grow_a : 0;
    const uint4* Xr = (const uint4*)(Xb + (size_t)srow * 128);
    short8 a[4];
    #pragma unroll
    for (int ks = 0; ks < 4; ++ks) {
        uint4 u = Xr[ks * 4 + quad];
        int kf = (ks * 32 + quad * 8) >> 2;
        float4 s0 = ((const float4*)cs)[kf];
        float4 s1 = ((const float4*)cs)[kf + 1];
        float4 c0 = ((const float4*)cb)[kf];
        float4 c1 = ((const float4*)cb)[kf + 1];
        short8 av;
        av[0] = (short)f2bf(fmaxf(fmaf(bflo(u.x), s0.x, c0.x), 0.f));
        av[1] = (short)f2bf(fmaxf(fmaf(bfhi(u.x), s0.y, c0.y), 0.f));
        av[2] = (short)f2bf(fmaxf(fmaf(bflo(u.y), s0.z, c0.z), 0.f));
        av[3] = (short)f2bf(fmaxf(fmaf(bfhi(u.y), s0.w, c0.w), 0.f));
        av[4] = (short)f2bf(fmaxf(fmaf(bflo(u.z), s1.x, c1.x), 0.f));
        av[5] = (short)f2bf(fmaxf(fmaf(bfhi(u.z), s1.y, c1.y), 0.f));
        av[6] = (short)f2bf(fmaxf(fmaf(bflo(u.w), s1.z, c1.z), 0.f));
        av[7] = (short)f2bf(fmaxf(fmaf(bfhi(u.w), s1.w, c1.w), 0.f));
        a[ks] = av;
    }
    __syncthreads();

    f32x4 acc[8] = {};
    #pragma unroll
    for (int ks = 0; ks < 4; ++ks) {
        int ko = ks * 32 + quad * 8;
        #pragma unroll
        for (int ct = 0; ct < 8; ++ct) {
            short8 b = *(const short8*)(&sB[(ct * 16 + m) * LDK + ko]);
            acc[ct] = __builtin_amdgcn_mfma_f32_16x16x32_bf16(a[ks], b, acc[ct], 0, 0, 0);
        }
    }
    #pragma unroll
    for (int r = 0; r < 4; ++r) {
        int grow = row0 + w * 16 + quad * 4 + r;
        if (grow >= nrows) continue;
        unsigned short* yr = Y + (size_t)grow * 128 + m;
        #pragma unroll
        for (int ct = 0; ct < 8; ++ct) yr[ct * 16] = f2bf(acc[ct][r]);
    }
}

// ---------------- pull-gather conv + fused GraphNorm stats ----------------
// quarter-wave rows; CSR rows padded to x8.
// Main loop: 24 edges/iter (6 rows in flight per quarter-wave) for L3 MLP;
// tails of 16 and 8. NO grid-wide signaling here (see R5 note).
__global__ __launch_bounds__(256) void k_gather(const unsigned short* __restrict__ H,
                                                unsigned short* __restrict__ O,
                                                const int* __restrict__ rowptr,
                                                const unsigned* __restrict__ csr_ew,
                                                const float* __restrict__ dinv,
                                                const float* __restrict__ bias,
                                                float* __restrict__ pS,
                                                float* __restrict__ pQ, int n) {
    __shared__ float sS[4][128];
    __shared__ float sQ[4][128];
    const int wid = threadIdx.x >> 6;
    const int node = blockIdx.x * 4 + wid;
    const int lane = threadIdx.x & 63;
    const int qw = lane >> 4;
    const int ql = lane & 15;
    const uint4* Hx = (const uint4*)H;
    float acc[8] = {};
    if (node < n) {
        float di = dinv[node];
        if (qw == 0) {
            uint4 u = Hx[(size_t)node * 16 + ql];
            float dd = di * di;
            float4 ba = ((const float4*)bias)[ql * 2];
            float4 bb = ((const float4*)bias)[ql * 2 + 1];
            acc[0] = bflo(u.x) * dd + ba.x; acc[1] = bfhi(u.x) * dd + ba.y;
            acc[2] = bflo(u.y) * dd + ba.z; acc[3] = bfhi(u.y) * dd + ba.w;
            acc[4] = bflo(u.z) * dd + bb.x; acc[5] = bfhi(u.z) * dd + bb.y;
            acc[6] = bflo(u.w) * dd + bb.z; acc[7] = bfhi(u.w) * dd + bb.w;
        }
        int j = rowptr[node];
        const int end = rowptr[node + 1];
        for (; j + 24 <= end; j += 24) {   // 24 edges: 6 per quarter-wave
            unsigned ew[6];
            #pragma unroll
            for (int q = 0; q < 6; ++q) ew[q] = csr_ew[j + 4 * q + qw];
            uint4 u[6];
            #pragma unroll
            for (int q = 0; q < 6; ++q)
                u[q] = Hx[((ew[q] >> 12) & 0xFFFF0u) + (unsigned)ql];
            #pragma unroll
            for (int q = 0; q < 6; ++q) {
                float nr = __uint_as_float(ew[q] << 16);
                acc[0] += bflo(u[q].x) * nr; acc[1] += bfhi(u[q].x) * nr;
                acc[2] += bflo(u[q].y) * nr; acc[3] += bfhi(u[q].y) * nr;
                acc[4] += bflo(u[q].z) * nr; acc[5] += bfhi(u[q].z) * nr;
                acc[6] += bflo(u[q].w) * nr; acc[7] += bfhi(u[q].w) * nr;
            }
        }
        if (j + 16 <= end) {   // 16 edges: 4 per quarter-wave
            unsigned ew[4];
            #pragma unroll
            for (int q = 0; q < 4; ++q) ew[q] = csr_ew[j + 4 * q + qw];
            uint4 u[4];
            #pragma unroll
            for (int q = 0; q < 4; ++q)
                u[q] = Hx[((ew[q] >> 12) & 0xFFFF0u) + (unsigned)ql];
            #pragma unroll
            for (int q = 0; q < 4; ++q) {
                float nr = __uint_as_float(ew[q] << 16);
                acc[0] += bflo(u[q].x) * nr; acc[1] += bfhi(u[q].x) * nr;
                acc[2] += bflo(u[q].y) * nr; acc[3] += bfhi(u[q].y) * nr;
                acc[4] += bflo(u[q].z) * nr; acc[5] += bfhi(u[q].z) * nr;
                acc[6] += bflo(u[q].w) * nr; acc[7] += bfhi(u[q].w) * nr;
            }
            j += 16;
        }
        if (j < end) {   // exactly 8 remain: 2 per quarter-wave
            unsigned ew[2];
            #pragma unroll
            for (int q = 0; q < 2; ++q) ew[q] = csr_ew[j + qw * 2 + q];
            uint4 u[2];
            #pragma unroll
            for (int q = 0; q < 2; ++q)
                u[q] = Hx[((ew[q] >> 12) & 0xFFFF0u) + (unsigned)ql];
            #pragma unroll
            for (int q = 0; q < 2; ++q) {
                float nr = __uint_as_float(ew[q] << 16);
                acc[0] += bflo(u[q].x) * nr; acc[1] += bfhi(u[q].x) * nr;
                acc[2] += bflo(u[q].y) * nr; acc[3] += bfhi(u[q].y) * nr;
                acc[4] += bflo(u[q].z) * nr; acc[5] += bfhi(u[q].z) * nr;
                acc[6] += bflo(u[q].w) * nr; acc[7] += bfhi(u[q].w) * nr;
            }
        }
        #pragma unroll
        for (int i = 0; i < 8; ++i) {
            acc[i] += __shfl_down(acc[i], 32);
            acc[i] += __shfl_down(acc[i], 16);
        }
    }
    if (qw == 0) {
        if (node < n) {
            unsigned short h[8];
            float v[8];
            #pragma unroll
            for (int i = 0; i < 8; ++i) {
                h[i] = f2bf(acc[i]);
                v[i] = __uint_as_float((unsigned)h[i] << 16);
                sS[wid][ql * 8 + i] = v[i];
                sQ[wid][ql * 8 + i] = v[i] * v[i];
            }
            uint4 o;
            o.x = (unsigned)h[0] | ((unsigned)h[1] << 16);
            o.y = (unsigned)h[2] | ((unsigned)h[3] << 16);
            o.z = (unsigned)h[4] | ((unsigned)h[5] << 16);
            o.w = (unsigned)h[6] | ((unsigned)h[7] << 16);
            *(uint4*)(O + (size_t)node * 128 + ql * 8) = o;
        } else {
            #pragma unroll
            for (int i = 0; i < 8; ++i) {
                sS[wid][ql * 8 + i] = 0.f;
                sQ[wid][ql * 8 + i] = 0.f;
            }
        }
    }
    __syncthreads();
    const int t = threadIdx.x;
    if (t < 128) {
        float s = sS[0][t] + sS[1][t] + sS[2][t] + sS[3][t];
        float q = sQ[0][t] + sQ[1][t] + sQ[2][t] + sQ[3][t];
        const int slotb = (blockIdx.x & 63) << 7;
        atomicAdd(&pS[slotb + t], s);
        atomicAdd(&pQ[slotb + t], q);
    }
}

// ---------------- Z = relu(affine(bufG)) @ M  (n x 2, fp32) ----------------
__global__ __launch_bounds__(256) void k_zproj(const unsigned short* __restrict__ Xb,
                                               const float* __restrict__ M,
                                               const float* __restrict__ cs,
                                               const float* __restrict__ cb,
                                               float2* __restrict__ Z, int n) {
    int node = blockIdx.x * 4 + (threadIdx.x >> 6);
    if (node >= n) return;
    int lane = threadIdx.x & 63;   // cols 2*lane, 2*lane+1
    unsigned u = ((const unsigned*)Xb)[(size_t)node * 64 + lane];
    int c0 = lane * 2;
    float a = fmaxf(fmaf(bflo(u), cs[c0], cb[c0]), 0.f);
    float b = fmaxf(fmaf(bfhi(u), cs[c0 + 1], cb[c0 + 1]), 0.f);
    float p0 = a * M[c0 * 2]     + b * M[(c0 + 1) * 2];
    float p1 = a * M[c0 * 2 + 1] + b * M[(c0 + 1) * 2 + 1];
    #pragma unroll
    for (int off = 32; off; off >>= 1) {
        p0 += __shfl_down(p0, off);
        p1 += __shfl_down(p1, off);
    }
    if (lane == 0) Z[node] = make_float2(p0, p1);
}

// ---------------- final: out[i] = dinv[i]^2*Z[i] + sum w*Z[s] + mb ----------------
__global__ __launch_bounds__(256) void k_gatherZ(const float2* __restrict__ Z,
                                                 const int* __restrict__ rowptr,
                                                 const unsigned* __restrict__ csr_ew,
                                                 const float* __restrict__ dinv,
                                                 const float* __restrict__ mb,
                                                 float* __restrict__ out, int n) {
    int wid = threadIdx.x >> 6;
    int lane = threadIdx.x & 63;
    int g = lane >> 4;
    int gl = lane & 15;
    int node = blockIdx.x * 16 + wid * 4 + g;
    if (node >= n) return;
    float2 acc = make_float2(0.f, 0.f);
    if (gl == 0) {
        float di = dinv[node];
        float2 z = Z[node];
        acc.x = z.x * di * di + mb[0];
        acc.y = z.y * di * di + mb[1];
    }
    int j = rowptr[node];
    const int end = rowptr[node + 1];
    for (int jj = j + gl; jj < end; jj += 16) {
        unsigned ew = csr_ew[jj];
        float2 z = Z[ew >> 16];
        float w = __uint_as_float(ew << 16);
        acc.x += z.x * w;
        acc.y += z.y * w;
    }
    #pragma unroll
    for (int off = 8; off; off >>= 1) {
        acc.x += __shfl_down(acc.x, off);
        acc.y += __shfl_down(acc.y, off);
    }
    if (gl == 0) {
        out[(size_t)node * 2]     = acc.x;
        out[(size_t)node * 2 + 1] = acc.y;
    }
}

// ---------------- GraphNorm finalize from 64 partial slots ----------------
__global__ void k_finstats(const float* __restrict__ pS, const float* __restrict__ pQ,
                           const float* __restrict__ w, const float* __restrict__ b,
                           const float* __restrict__ alpha,
                           float* __restrict__ colscale, float* __restrict__ colshift,
                           int n) {
    int c = threadIdx.x;
    if (c >= 128) return;
    float s = 0.f, q = 0.f;
    #pragma unroll 8
    for (int blk = 0; blk < 64; ++blk) {
        s += pS[blk * 128 + c];
        q += pQ[blk * 128 + c];
    }
    float inv_n = 1.0f / (float)n;
    float m = s * inv_n;
    float eh2 = q * inv_n;
    float a = alpha[c];
    float var = eh2 - (2.0f * a - a * a) * m * m;
    float scale = rsqrtf(var + GN_EPS) * w[c];
    colscale[c] = scale;
    colshift[c] = b[c] - a * m * scale;
}

extern "C" void kernel_launch(void* const* d_in, const int* in_sizes, int n_in,
                              void* d_out, int out_size, void* d_ws, size_t ws_size,
                              hipStream_t stream) {
    const float* x    = (const float*)d_in[0];
    const int*   ei   = (const int*)  d_in[1];
    const float* W1   = (const float*)d_in[2];
    const float* b1   = (const float*)d_in[3];
    const float* W2   = (const float*)d_in[4];
    const float* b2   = (const float*)d_in[5];
    const float* W3   = (const float*)d_in[6];
    const float* b3   = (const float*)d_in[7];
    const float* gn1w = (const float*)d_in[8];
    const float* gn1b = (const float*)d_in[9];
    const float* gn1a = (const float*)d_in[10];
    const float* gn2w = (const float*)d_in[11];
    const float* gn2b = (const float*)d_in[12];
    const float* gn2a = (const float*)d_in[13];
    const float* Wout = (const float*)d_in[14];
    const float* bout = (const float*)d_in[15];
    float* out = (float*)d_out;

    const int n = in_sizes[0] / 128;
    const int e = in_sizes[1] / 2;
    const int* srcI = ei;
    const int* dstI = ei + e;

    // chunking for the histogram CSR build (chunk forced to multiple of 4)
    const int chunk = (((e + HIST_C - 1) / HIST_C) + 3) & ~3;
    const int nchunks = (e + chunk - 1) / chunk;

    // bump allocator, 16B-aligned blocks; [pS..csr_ew] is one contiguous zeroed region
    char* base = (char*)d_ws;
    size_t off = 0;
    auto take = [&](size_t bytes) -> void* {
        void* r = base + off;
        off += (bytes + 15) & ~(size_t)15;
        return r;
    };
    unsigned short* bufH = (unsigned short*)take((size_t)n * 256);   // n*128 bf16
    unsigned short* bufG = (unsigned short*)take((size_t)n * 256);   // n*128 bf16
    float* dinv     = (float*)take((size_t)n * 4);
    float* colscale = (float*)take(128 * 4);
    float* colshift = (float*)take(128 * 4);
    int*   rowptr   = (int*)take(((size_t)n + 1) * 4);
    int*   partial  = (int*)take(256 * 4);              // per-256-node padded partials
    unsigned short* Wt = (unsigned short*)take(2 * 16384 * 2);
    float* M        = (float*)take(256 * 4);
    float* mb       = (float*)take(2 * 4);
    float2* Z       = (float2*)take((size_t)n * 8);
    int*   degi     = (int*)take((size_t)n * 4);
    unsigned short* cnt = (unsigned short*)take((size_t)nchunks * n * 2);
    unsigned short* pos = (unsigned short*)take((size_t)e * 2);
    // ---- zeroed region starts here ----
    float* pS       = (float*)take(2 * 64 * 128 * 4);   // layer1 [0,8192), layer2 [8192,16384)
    float* pQ       = (float*)take(2 * 64 * 128 * 4);
    size_t csr_cap  = (size_t)e + 8 * (size_t)n;        // pad-8 worst case
    unsigned* csr_ew = (unsigned*)take(csr_cap * 4);
    size_t zbytes   = (size_t)((base + off) - (char*)pS);

    const int nb = (n + SCAN_CHUNK - 1) / SCAN_CHUNK;
    const int gemmGrid = (n + 63) / 64;
    const int gathGrid = (n + 3) / 4;

    // ---- CSR build (atomic-free) + weight prep ----
    hipMemsetAsync(pS, 0, zbytes, stream);
    k_prep_hist<<<3 + nchunks, 256, 0, stream>>>(W1, W2, W3, Wout, b3, bout,
                                                 Wt, M, mb, dstI, cnt, pos, e, n, chunk);
    k_reduce<<<(n + 255) / 256, 256, 0, stream>>>(cnt, degi, partial, n, nchunks);
    k_scanfinal<<<nb, 256, 0, stream>>>(degi, partial, rowptr, dinv, n, nb);
    k_fill<<<(e + 1023) / 1024, 256, 0, stream>>>(srcI, dstI, pos, cnt, rowptr,
                                                  dinv, csr_ew, e, n, chunk);

    // layer 1
    k_gemm_f32<<<gemmGrid, 256, 0, stream>>>(x, Wt, bufH, n);
    k_gather<<<gathGrid, 256, 0, stream>>>(bufH, bufG, rowptr, csr_ew, dinv, b1, pS, pQ, n);
    k_finstats<<<1, 128, 0, stream>>>(pS, pQ, gn1w, gn1b, gn1a, colscale, colshift, n);

    // layer 2
    k_gemm_bf<<<gemmGrid, 256, 0, stream>>>(bufG, Wt + 16384, bufH, colscale, colshift, n);
    k_gather<<<gathGrid, 256, 0, stream>>>(bufH, bufG, rowptr, csr_ew, dinv, b2,
                                           pS + 8192, pQ + 8192, n);
    k_finstats<<<1, 128, 0, stream>>>(pS + 8192, pQ + 8192, gn2w, gn2b, gn2a,
                                      colscale, colshift, n);

    // layer 3 collapsed: Z = relu(affine(bufG)) @ (W3@Wout); out = A_hat * Z + mb
    k_zproj<<<gathGrid, 256, 0, stream>>>(bufG, M, colscale, colshift, Z, n);
    k_gatherZ<<<(n + 15) / 16, 256, 0, stream>>>(Z, rowptr, csr_ew, dinv, mb, out, n);
}